// Round 6
// baseline (50.502 us; speedup 1.0000x reference)
//
#include <hip/hip_runtime.h>
#include <math.h>

typedef float f32x2 __attribute__((ext_vector_type(2)));
typedef float f32x4 __attribute__((ext_vector_type(4)));
typedef int   i32x4 __attribute__((ext_vector_type(4)));

static constexpr int B_ = 4;
static constexpr int L_ = 256;
static constexpr int K_ = 256;
static constexpr int H_ = 768;
static constexpr int VAL_SIZE_ = 10000;
static constexpr float INV_TEMPER = 0.03608439182435161f; // 1/sqrt(768)

// ---------------- non-temporal access helpers (native vector types) --------
__device__ __forceinline__ float4 nt_load4(const float* p) {
  f32x4 v = __builtin_nontemporal_load(reinterpret_cast<const f32x4*>(p));
  return make_float4(v.x, v.y, v.z, v.w);
}
__device__ __forceinline__ int4 nt_load4i(const int* p) {
  i32x4 v = __builtin_nontemporal_load(reinterpret_cast<const i32x4*>(p));
  return make_int4(v.x, v.y, v.z, v.w);
}
__device__ __forceinline__ void nt_store4(float* p, float4 v) {
  f32x4 n = {v.x, v.y, v.z, v.w};
  __builtin_nontemporal_store(n, reinterpret_cast<f32x4*>(p));
}

// ---------------- bf16 helpers (RNE) ----------------
__device__ __forceinline__ unsigned bf16_rne(float f) {
  unsigned x = __float_as_uint(f);
  return (x + 0x7fffu + ((x >> 16) & 1u)) >> 16;
}
__device__ __forceinline__ float bf_lo(unsigned u) { return __uint_as_float(u << 16); }
__device__ __forceinline__ float bf_hi(unsigned u) { return __uint_as_float(u & 0xffff0000u); }

// ---------------- fp8 e4m3fn (OCP) helpers ----------------
#if __has_builtin(__builtin_amdgcn_cvt_pk_fp8_f32)
#define HW_FP8_ENC 1
#endif
#if __has_builtin(__builtin_amdgcn_cvt_pk_f32_fp8)
#define HW_FP8_DEC 1
#endif

__device__ __forceinline__ unsigned fp8_enc1(float f) {
  unsigned s = (__float_as_uint(f) >> 31) << 7;
  float af = fminf(fabsf(f), 448.0f);
  unsigned em;
  if (af < 0.015625f) {
    em = (unsigned)rintf(af * 512.0f);
  } else {
    unsigned m = __float_as_uint(af);
    m += 0x7ffffu + ((m >> 20) & 1u);
    em = (m >> 20) - (120u << 3);
  }
  return s | em;
}
__device__ __forceinline__ float fp8_dec1(unsigned b) {
  unsigned em = b & 0x7fu;
  unsigned sbit = (b & 0x80u) << 24;
  float n = __uint_as_float(sbit | ((em + 960u) << 20));
  float sub = __uint_as_float(sbit | 0x3F800000u) * (float)em * 0.001953125f;
  return em >= 8u ? n : sub;
}
__device__ __forceinline__ unsigned fp8_enc4(float a, float b, float c, float d) {
#ifdef HW_FP8_ENC
  int w = 0;
  w = __builtin_amdgcn_cvt_pk_fp8_f32(a, b, w, false);
  w = __builtin_amdgcn_cvt_pk_fp8_f32(c, d, w, true);
  return (unsigned)w;
#else
  return fp8_enc1(a) | (fp8_enc1(b) << 8) | (fp8_enc1(c) << 16) | (fp8_enc1(d) << 24);
#endif
}
__device__ __forceinline__ void fp8_dec4(unsigned w, float* o) {
#ifdef HW_FP8_DEC
  f32x2 lo = __builtin_amdgcn_cvt_pk_f32_fp8((int)w, false);
  f32x2 hi = __builtin_amdgcn_cvt_pk_f32_fp8((int)w, true);
  o[0] = lo.x; o[1] = lo.y; o[2] = hi.x; o[3] = hi.y;
#else
  o[0] = fp8_dec1(w & 0xffu);
  o[1] = fp8_dec1((w >> 8) & 0xffu);
  o[2] = fp8_dec1((w >> 16) & 0xffu);
  o[3] = fp8_dec1(w >> 24);
#endif
}

static constexpr int TBLK = (K_ / 64) * (H_ / 64) * B_;    // 192 transpose blocks
static constexpr int SBLK = (L_ / 4) * B_;                 // 256 score blocks
static constexpr int CBLK = (VAL_SIZE_ * H_) / 4096;       // 1875 convert blocks

// ---------------------------------------------------------------------------
// Kernel 1: gather key embedding rows, transpose to bf16 ET16[b][h][k].
// grid TBLK, block 256.
// ---------------------------------------------------------------------------
__global__ __launch_bounds__(256)
void k_gather_keys_T(const int* __restrict__ key_seq,
                     const float* __restrict__ key_emb,
                     unsigned short* __restrict__ ET16) {
  __shared__ float tile[64][65];
  const int blk  = blockIdx.x;
  const int kb   = (blk % (K_ / 64)) * 64;
  const int hb   = ((blk / (K_ / 64)) % (H_ / 64)) * 64;
  const int b    = blk / ((K_ / 64) * (H_ / 64));
  const int t    = threadIdx.x;
  const int sub  = t >> 6;
  const int lane = t & 63;

#pragma unroll
  for (int p = 0; p < 16; ++p) {
    const int kl  = p * 4 + sub;
    const int row = key_seq[b * K_ + kb + kl];              // wave-uniform
    tile[kl][lane] = key_emb[(size_t)row * H_ + hb + lane]; // coalesced
  }
  __syncthreads();
#pragma unroll
  for (int p = 0; p < 16; ++p) {
    const int hl = p * 4 + sub;
    ET16[((size_t)b * H_ + hb + hl) * K_ + kb + lane] =
        (unsigned short)bf16_rne(tile[lane][hl]);
  }
}

// ---------------------------------------------------------------------------
// Kernel 2: scores + masked softmax (blocks [0,SBLK)); val-table f32->fp8
// conversion (blocks [SBLK, SBLK+CBLK), per-instruction-contiguous lanes).
// block 256.
// ---------------------------------------------------------------------------
__global__ __launch_bounds__(256)
void k_scores_convert(const float* __restrict__ hidden,
                      const unsigned short* __restrict__ ET16,
                      const int* __restrict__ mask,
                      const float* __restrict__ vtab,
                      float* __restrict__ P,
                      unsigned char* __restrict__ VT8) {
  __shared__ float  hid[4 * H_];    // 12 KB
  __shared__ float4 part[4][256];   // 16 KB
  const int t = threadIdx.x;

  if (blockIdx.x >= SBLK) {
    // ---- val table f32 -> fp8; block covers 4096 contiguous floats ----
    const size_t base = (size_t)(blockIdx.x - SBLK) * 4096;
#pragma unroll
    for (int c = 0; c < 4; ++c) {
      const size_t e0 = base + (size_t)c * 1024 + (size_t)t * 4;
      const float4 a = nt_load4(vtab + e0);
      *reinterpret_cast<unsigned*>(VT8 + e0) = fp8_enc4(a.x, a.y, a.z, a.w);
    }
    return;
  }

  const int l0 = (blockIdx.x % (L_ / 4)) * 4;
  const int b  = blockIdx.x / (L_ / 4);

  const float* hsrc = hidden + ((size_t)b * L_ + l0) * H_;
  for (int i = t; i < 4 * H_; i += 256) hid[i] = hsrc[i];
  __syncthreads();

  const int kq = t & 63;
  const int hq = t >> 6;

  float4 acc[4];
#pragma unroll
  for (int l = 0; l < 4; ++l) acc[l] = make_float4(0.f, 0.f, 0.f, 0.f);

  const unsigned short* etp =
      ET16 + (size_t)b * H_ * K_ + (size_t)(hq * 192) * K_ + kq * 4;
  const int hbase = hq * 192;
#pragma unroll 4
  for (int hh = 0; hh < 192; ++hh) {
    const uint2 e = *reinterpret_cast<const uint2*>(etp + (size_t)hh * K_);
    const float e0 = bf_lo(e.x), e1 = bf_hi(e.x);
    const float e2 = bf_lo(e.y), e3 = bf_hi(e.y);
#pragma unroll
    for (int l = 0; l < 4; ++l) {
      const float hv = hid[l * H_ + hbase + hh];  // LDS broadcast
      acc[l].x += hv * e0;
      acc[l].y += hv * e1;
      acc[l].z += hv * e2;
      acc[l].w += hv * e3;
    }
  }
#pragma unroll
  for (int l = 0; l < 4; ++l) part[l][t] = acc[l];
  __syncthreads();

  const int kq2 = t & 63;
  const int l2  = t >> 6;
  float4 a = part[l2][kq2];
  const float4 b1 = part[l2][64 + kq2];
  const float4 c  = part[l2][128 + kq2];
  const float4 d  = part[l2][192 + kq2];
  a.x += b1.x + c.x + d.x;
  a.y += b1.y + c.y + d.y;
  a.z += b1.z + c.z + d.z;
  a.w += b1.w + c.w + d.w;

  const int lrow = l0 + l2;
  const int4 m4 = nt_load4i(mask + ((size_t)b * L_ + lrow) * K_ + kq2 * 4);
  float4 ex;
  ex.x = (m4.x > 0) ? expf(a.x * INV_TEMPER) : 0.f;
  ex.y = (m4.y > 0) ? expf(a.y * INV_TEMPER) : 0.f;
  ex.z = (m4.z > 0) ? expf(a.z * INV_TEMPER) : 0.f;
  ex.w = (m4.w > 0) ? expf(a.w * INV_TEMPER) : 0.f;

  float s = ex.x + ex.y + ex.z + ex.w;
#pragma unroll
  for (int off = 32; off > 0; off >>= 1) s += __shfl_down(s, off);
  const float tot = __shfl(s, 0) + 1e-10f;

  float4 p4;
  p4.x = ex.x / tot;
  p4.y = ex.y / tot;
  p4.z = ex.z / tot;
  p4.w = ex.w / tot;
  *reinterpret_cast<float4*>(P + ((size_t)b * L_ + lrow) * K_ + kq2 * 4) = p4;
}

// ---------------------------------------------------------------------------
// Kernel 3: o = sum_k p * V8[idx] + hidden, h-split across XCD halves.
// Two blocks per (b,l): hhalf = (bid&7)>>2 selects which 384-byte half of
// each fp8 value row this block gathers (and which output half it writes).
// On the round-robin blockIdx->XCD mapping, XCDs 0-3 then only touch the
// low 3.75 MB of the table, XCDs 4-7 the high 3.75 MB -> each fits its
// 4 MB L2. Disjoint outputs: no combine, no atomics. 8 slices x 48 lanes.
// grid 2048, block 384.
// ---------------------------------------------------------------------------
__global__ __launch_bounds__(384)
void k_pv_add(const float* __restrict__ hidden,
              const int* __restrict__ vmat,
              const float* __restrict__ P,
              const unsigned char* __restrict__ VT8,
              float* __restrict__ out) {
  __shared__ float pw[K_];
  __shared__ int   vidx[K_];
  __shared__ int   wcounts[4];
  __shared__ float osum[7][384];   // slices 0..6; slice 7 keeps regs

  const int bid   = blockIdx.x;
  const int xcd   = bid & 7;
  const int hhalf = xcd >> 2;                      // 0: h<384, 1: h>=384
  const int pair  = ((bid >> 3) << 2) | (xcd & 3); // 0..1023
  const int b = pair >> 8;
  const int l = pair & 255;
  const int t = threadIdx.x;
  const int lane = t & 63;
  const int wid  = t >> 6;
  const size_t rowoff = ((size_t)b * L_ + l) * K_;

  // deterministic compaction of nonzero p (waves 0..3 fully active)
  float pval = 0.f;
  bool pred = false;
  unsigned long long mball = 0;
  if (t < K_) {
    pval = P[rowoff + t];
    pred = (pval != 0.f);
    mball = __ballot(pred);
    if (lane == 0) wcounts[wid] = (int)__popcll(mball);
  }
  __syncthreads();
  const int n = wcounts[0] + wcounts[1] + wcounts[2] + wcounts[3];
  if (t < K_ && pred) {
    int base = 0;
#pragma unroll
    for (int w = 0; w < 4; ++w)
      if (w < wid) base += wcounts[w];
    const int pos = base + (int)__popcll(mball & ((1ull << lane) - 1ull));
    pw[pos]   = pval;
    vidx[pos] = vmat[rowoff + t];
  }
  __syncthreads();

  const int slice = t / 48;                 // 0..7
  const int g     = t % 48;                 // 8 floats each
  const int hoff  = hhalf * 384 + g * 8;    // byte==elem offset in fp8 row

  float acc[8];
#pragma unroll
  for (int i = 0; i < 8; ++i) acc[i] = 0.f;

#pragma unroll 4
  for (int j = slice; j < n; j += 8) {
    const float w = pw[j];                  // LDS broadcast (2 addrs/wave)
    const uint2 v = *reinterpret_cast<const uint2*>(
        VT8 + (size_t)vidx[j] * H_ + hoff); // 8B, 48 lanes = 384B line-aligned
    float f[8];
    fp8_dec4(v.x, f);
    fp8_dec4(v.y, f + 4);
#pragma unroll
    for (int i = 0; i < 8; ++i) acc[i] += w * f[i];
  }

  if (slice < 7) {
    *reinterpret_cast<float4*>(&osum[slice][g * 8]) =
        make_float4(acc[0], acc[1], acc[2], acc[3]);
    *reinterpret_cast<float4*>(&osum[slice][g * 8 + 4]) =
        make_float4(acc[4], acc[5], acc[6], acc[7]);
  }
  __syncthreads();
  if (slice == 7) {
    const float* hrow = hidden + ((size_t)b * L_ + l) * H_ + hoff;
    const float4 h0 = nt_load4(hrow);
    const float4 h1 = nt_load4(hrow + 4);
    float r[8];
#pragma unroll
    for (int i = 0; i < 8; ++i) {
      float sum = acc[i];
#pragma unroll
      for (int s = 0; s < 7; ++s) sum += osum[s][g * 8 + i];
      r[i] = sum;
    }
    float4 r0 = make_float4(r[0] + h0.x, r[1] + h0.y, r[2] + h0.z, r[3] + h0.w);
    float4 r1 = make_float4(r[4] + h1.x, r[5] + h1.y, r[6] + h1.z, r[7] + h1.w);
    float* orow = out + ((size_t)b * L_ + l) * H_ + hoff;
    nt_store4(orow, r0);
    nt_store4(orow + 4, r1);
  }
}

// ---------------------------------------------------------------------------
extern "C" void kernel_launch(void* const* d_in, const int* in_sizes, int n_in,
                              void* d_out, int out_size, void* d_ws, size_t ws_size,
                              hipStream_t stream) {
  (void)in_sizes; (void)n_in; (void)out_size; (void)ws_size;
  const float* hidden  = (const float*)d_in[0];
  const int*   key_seq = (const int*)d_in[1];
  const int*   vmat    = (const int*)d_in[2];
  const int*   mask    = (const int*)d_in[3];
  const float* key_emb = (const float*)d_in[4];
  const float* val_emb = (const float*)d_in[5];
  float* out = (float*)d_out;

  // ws layout (16B-aligned):
  //   VT8 : VAL_SIZE*H bytes  = 7,680,000 B
  //   ET16: B*H*K ushort      = 1,572,864 B
  //   P   : B*L*K float       = 1,048,576 B
  unsigned char*  VT8  = (unsigned char*)d_ws;
  unsigned short* ET16 = (unsigned short*)(VT8 + (size_t)VAL_SIZE_ * H_);
  float*          P    = (float*)(ET16 + (size_t)B_ * H_ * K_);

  k_gather_keys_T<<<TBLK, 256, 0, stream>>>(key_seq, key_emb, ET16);
  k_scores_convert<<<SBLK + CBLK, 256, 0, stream>>>(hidden, ET16, mask,
                                                    val_emb, P, VT8);
  k_pv_add<<<2048, 384, 0, stream>>>(hidden, vmat, P, VT8, out);
}

// Round 7
// 39.186 us; speedup vs baseline: 1.2887x; 1.2887x over previous
//
#include <hip/hip_runtime.h>
#include <math.h>

typedef float    f32x2 __attribute__((ext_vector_type(2)));
typedef float    f32x4 __attribute__((ext_vector_type(4)));
typedef _Float16 f16x2 __attribute__((ext_vector_type(2)));

static constexpr int B_ = 4;
static constexpr int L_ = 256;
static constexpr int K_ = 256;
static constexpr int H_ = 768;
static constexpr int H2_ = H_ / 2;       // 384 f16-pairs per row
static constexpr int VAL_SIZE_ = 10000;
static constexpr float INV_TEMPER = 0.03608439182435161f; // 1/sqrt(768)

// ---------------- f16 pair helpers ----------------
__device__ __forceinline__ unsigned pack_f16x2(float a, float b) {
  f16x2 p = {(_Float16)a, (_Float16)b};   // RNE converts
  return __builtin_bit_cast(unsigned, p);
}
__device__ __forceinline__ float fdot2u(unsigned a, unsigned b, float c) {
#if __has_builtin(__builtin_amdgcn_fdot2)
  return __builtin_amdgcn_fdot2(__builtin_bit_cast(f16x2, a),
                                __builtin_bit_cast(f16x2, b), c, false);
#else
  f16x2 va = __builtin_bit_cast(f16x2, a);
  f16x2 vb = __builtin_bit_cast(f16x2, b);
  return c + (float)va.x * (float)vb.x + (float)va.y * (float)vb.y;
#endif
}

// ---------------- non-temporal load (native vec type) ----------------
__device__ __forceinline__ float4 nt_load4(const float* p) {
  f32x4 v = __builtin_nontemporal_load(reinterpret_cast<const f32x4*>(p));
  return make_float4(v.x, v.y, v.z, v.w);
}

// ---------------- fp8 e4m3fn (OCP) helpers ----------------
#if __has_builtin(__builtin_amdgcn_cvt_pk_fp8_f32)
#define HW_FP8_ENC 1
#endif
#if __has_builtin(__builtin_amdgcn_cvt_pk_f32_fp8)
#define HW_FP8_DEC 1
#endif

__device__ __forceinline__ unsigned fp8_enc1(float f) {
  unsigned s = (__float_as_uint(f) >> 31) << 7;
  float af = fminf(fabsf(f), 448.0f);
  unsigned em;
  if (af < 0.015625f) {
    em = (unsigned)rintf(af * 512.0f);
  } else {
    unsigned m = __float_as_uint(af);
    m += 0x7ffffu + ((m >> 20) & 1u);
    em = (m >> 20) - (120u << 3);
  }
  return s | em;
}
__device__ __forceinline__ float fp8_dec1(unsigned b) {
  unsigned em = b & 0x7fu;
  unsigned sbit = (b & 0x80u) << 24;
  float n = __uint_as_float(sbit | ((em + 960u) << 20));
  float sub = __uint_as_float(sbit | 0x3F800000u) * (float)em * 0.001953125f;
  return em >= 8u ? n : sub;
}
__device__ __forceinline__ unsigned fp8_enc4(float a, float b, float c, float d) {
#ifdef HW_FP8_ENC
  int w = 0;
  w = __builtin_amdgcn_cvt_pk_fp8_f32(a, b, w, false);
  w = __builtin_amdgcn_cvt_pk_fp8_f32(c, d, w, true);
  return (unsigned)w;
#else
  return fp8_enc1(a) | (fp8_enc1(b) << 8) | (fp8_enc1(c) << 16) | (fp8_enc1(d) << 24);
#endif
}
__device__ __forceinline__ void fp8_dec4(unsigned w, float* o) {
#ifdef HW_FP8_DEC
  f32x2 lo = __builtin_amdgcn_cvt_pk_f32_fp8((int)w, false);
  f32x2 hi = __builtin_amdgcn_cvt_pk_f32_fp8((int)w, true);
  o[0] = lo.x; o[1] = lo.y; o[2] = hi.x; o[3] = hi.y;
#else
  o[0] = fp8_dec1(w & 0xffu);
  o[1] = fp8_dec1((w >> 8) & 0xffu);
  o[2] = fp8_dec1((w >> 16) & 0xffu);
  o[3] = fp8_dec1(w >> 24);
#endif
}

static constexpr int TBLK = (K_ / 64) * (H_ / 64) * B_;    // 192 transpose blocks
static constexpr int SBLK = (L_ / 4) * B_;                 // 256 score blocks
static constexpr int CBLK = (VAL_SIZE_ * H_) / 4096;       // 1875 convert blocks

// ---------------------------------------------------------------------------
// Kernel 1: gather key embedding rows, transpose to f16-pair ET2[b][h2][k]
// (uint = f16 pair (2*h2, 2*h2+1)). grid TBLK, block 256.
// ---------------------------------------------------------------------------
__global__ __launch_bounds__(256)
void k_gather_keys_T(const int* __restrict__ key_seq,
                     const float* __restrict__ key_emb,
                     unsigned* __restrict__ ET2) {
  __shared__ float tile[64][65];
  const int blk  = blockIdx.x;
  const int kb   = (blk % (K_ / 64)) * 64;
  const int hb   = ((blk / (K_ / 64)) % (H_ / 64)) * 64;
  const int b    = blk / ((K_ / 64) * (H_ / 64));
  const int t    = threadIdx.x;
  const int sub  = t >> 6;
  const int lane = t & 63;

#pragma unroll
  for (int p = 0; p < 16; ++p) {
    const int kl  = p * 4 + sub;
    const int row = key_seq[b * K_ + kb + kl];              // wave-uniform
    tile[kl][lane] = key_emb[(size_t)row * H_ + hb + lane]; // coalesced
  }
  __syncthreads();
#pragma unroll
  for (int p = 0; p < 8; ++p) {
    const int hl2 = p * 4 + sub;                            // 0..31
    ET2[((size_t)b * H2_ + (hb >> 1) + hl2) * K_ + kb + lane] =
        pack_f16x2(tile[lane][2 * hl2], tile[lane][2 * hl2 + 1]);
  }
}

// ---------------------------------------------------------------------------
// Kernel 2: scores + masked softmax via v_dot2 f16 (blocks [0,SBLK));
// val-table f32->fp8 conversion (blocks [SBLK, SBLK+CBLK)). block 256.
// ---------------------------------------------------------------------------
__global__ __launch_bounds__(256)
void k_scores_convert(const float* __restrict__ hidden,
                      const unsigned* __restrict__ ET2,
                      const int* __restrict__ mask,
                      const float* __restrict__ vtab,
                      float* __restrict__ P,
                      unsigned char* __restrict__ VT8) {
  __shared__ unsigned hid2[4 * H2_];  // 6 KB (f16 pairs along h)
  __shared__ float4   part[4][256];   // 16 KB
  const int t = threadIdx.x;

  if (blockIdx.x >= SBLK) {
    // ---- val table f32 -> fp8; block covers 4096 contiguous floats ----
    const size_t base = (size_t)(blockIdx.x - SBLK) * 4096;
#pragma unroll
    for (int c = 0; c < 4; ++c) {
      const size_t e0 = base + (size_t)c * 1024 + (size_t)t * 4;
      const float4 a = nt_load4(vtab + e0);
      *reinterpret_cast<unsigned*>(VT8 + e0) = fp8_enc4(a.x, a.y, a.z, a.w);
    }
    return;
  }

  const int l0 = (blockIdx.x % (L_ / 4)) * 4;
  const int b  = blockIdx.x / (L_ / 4);

  // stage 4 hidden rows as packed f16 pairs
  const float* hsrc = hidden + ((size_t)b * L_ + l0) * H_;
  for (int i = t; i < 4 * H2_; i += 256) {
    const float2 hv = *reinterpret_cast<const float2*>(hsrc + 2 * i);
    hid2[i] = pack_f16x2(hv.x, hv.y);
  }
  __syncthreads();

  const int kq = t & 63;   // k-quad: k = kq*4 .. kq*4+3
  const int hq = t >> 6;   // h2-chunk: h2 in [hq*96, hq*96+96)

  float4 acc[4];
#pragma unroll
  for (int l = 0; l < 4; ++l) acc[l] = make_float4(0.f, 0.f, 0.f, 0.f);

  const unsigned* etp =
      ET2 + (size_t)b * H2_ * K_ + (size_t)(hq * 96) * K_ + kq * 4;
  const int hbase2 = hq * 96;
#pragma unroll 4
  for (int hh = 0; hh < 96; ++hh) {
    const uint4 e = *reinterpret_cast<const uint4*>(etp + (size_t)hh * K_);
#pragma unroll
    for (int l = 0; l < 4; ++l) {
      const unsigned hv2 = hid2[l * H2_ + hbase2 + hh];  // LDS broadcast
      acc[l].x = fdot2u(e.x, hv2, acc[l].x);
      acc[l].y = fdot2u(e.y, hv2, acc[l].y);
      acc[l].z = fdot2u(e.z, hv2, acc[l].z);
      acc[l].w = fdot2u(e.w, hv2, acc[l].w);
    }
  }
#pragma unroll
  for (int l = 0; l < 4; ++l) part[l][t] = acc[l];
  __syncthreads();

  const int kq2 = t & 63;
  const int l2  = t >> 6;
  float4 a = part[l2][kq2];
  const float4 b1 = part[l2][64 + kq2];
  const float4 c  = part[l2][128 + kq2];
  const float4 d  = part[l2][192 + kq2];
  a.x += b1.x + c.x + d.x;
  a.y += b1.y + c.y + d.y;
  a.z += b1.z + c.z + d.z;
  a.w += b1.w + c.w + d.w;

  const int lrow = l0 + l2;
  const int4 m4 = *reinterpret_cast<const int4*>(
      mask + ((size_t)b * L_ + lrow) * K_ + kq2 * 4);
  float4 ex;
  ex.x = (m4.x > 0) ? expf(a.x * INV_TEMPER) : 0.f;
  ex.y = (m4.y > 0) ? expf(a.y * INV_TEMPER) : 0.f;
  ex.z = (m4.z > 0) ? expf(a.z * INV_TEMPER) : 0.f;
  ex.w = (m4.w > 0) ? expf(a.w * INV_TEMPER) : 0.f;

  float s = ex.x + ex.y + ex.z + ex.w;
#pragma unroll
  for (int off = 32; off > 0; off >>= 1) s += __shfl_down(s, off);
  const float tot = __shfl(s, 0) + 1e-10f;

  float4 p4;
  p4.x = ex.x / tot;
  p4.y = ex.y / tot;
  p4.z = ex.z / tot;
  p4.w = ex.w / tot;
  *reinterpret_cast<float4*>(P + ((size_t)b * L_ + lrow) * K_ + kq2 * 4) = p4;
}

// ---------------------------------------------------------------------------
// Kernel 3 (r4 structure): o = sum_k p * V8[idx] + hidden, skipping p==0 via
// deterministic compaction. 4 slices x 96 lanes, uint2 (8 fp8) per lane.
// grid (L, B), block 384.
// ---------------------------------------------------------------------------
__global__ __launch_bounds__(384)
void k_pv_add(const float* __restrict__ hidden,
              const int* __restrict__ vmat,
              const float* __restrict__ P,
              const unsigned char* __restrict__ VT8,
              float* __restrict__ out) {
  __shared__ float pw[K_];
  __shared__ int   vidx[K_];
  __shared__ int   wcounts[4];
  __shared__ float osum[3][H_];   // slices 0..2; slice 3 keeps regs

  const int l = blockIdx.x;
  const int b = blockIdx.y;
  const int t = threadIdx.x;
  const int lane = t & 63;
  const int wid  = t >> 6;
  const size_t rowoff = ((size_t)b * L_ + l) * K_;

  // deterministic compaction of nonzero p (waves 0..3 fully active)
  float pval = 0.f;
  bool pred = false;
  unsigned long long mball = 0;
  if (t < K_) {
    pval = P[rowoff + t];
    pred = (pval != 0.f);
    mball = __ballot(pred);
    if (lane == 0) wcounts[wid] = (int)__popcll(mball);
  }
  __syncthreads();
  const int n = wcounts[0] + wcounts[1] + wcounts[2] + wcounts[3];
  if (t < K_ && pred) {
    int base = 0;
#pragma unroll
    for (int w = 0; w < 4; ++w)
      if (w < wid) base += wcounts[w];
    const int pos = base + (int)__popcll(mball & ((1ull << lane) - 1ull));
    pw[pos]   = pval;
    vidx[pos] = vmat[rowoff + t];
  }
  __syncthreads();

  const int slice = t / 96;   // 0..3
  const int g     = t % 96;   // h-lane: h in [g*8, g*8+8)

  float acc[8];
#pragma unroll
  for (int i = 0; i < 8; ++i) acc[i] = 0.f;

#pragma unroll 4
  for (int j = slice; j < n; j += 4) {
    const float w = pw[j];                        // LDS broadcast
    const uint2 v = *reinterpret_cast<const uint2*>(
        VT8 + (size_t)vidx[j] * H_ + g * 8);      // 8B coalesced fp8
    float f[8];
    fp8_dec4(v.x, f);
    fp8_dec4(v.y, f + 4);
#pragma unroll
    for (int i = 0; i < 8; ++i) acc[i] += w * f[i];
  }

  if (slice < 3) {
    *reinterpret_cast<float4*>(&osum[slice][g * 8]) =
        make_float4(acc[0], acc[1], acc[2], acc[3]);
    *reinterpret_cast<float4*>(&osum[slice][g * 8 + 4]) =
        make_float4(acc[4], acc[5], acc[6], acc[7]);
  }
  __syncthreads();
  if (slice == 3) {
    const float* hrow = hidden + ((size_t)b * L_ + l) * H_ + g * 8;
    const float4 h0 = *reinterpret_cast<const float4*>(hrow);
    const float4 h1 = *reinterpret_cast<const float4*>(hrow + 4);
    float r[8];
#pragma unroll
    for (int i = 0; i < 8; ++i) {
      float sum = acc[i];
#pragma unroll
      for (int s = 0; s < 3; ++s) sum += osum[s][g * 8 + i];
      r[i] = sum;
    }
    float4 r0 = make_float4(r[0] + h0.x, r[1] + h0.y, r[2] + h0.z, r[3] + h0.w);
    float4 r1 = make_float4(r[4] + h1.x, r[5] + h1.y, r[6] + h1.z, r[7] + h1.w);
    float* orow = out + ((size_t)b * L_ + l) * H_ + g * 8;
    *reinterpret_cast<float4*>(orow)     = r0;
    *reinterpret_cast<float4*>(orow + 4) = r1;
  }
}

// ---------------------------------------------------------------------------
extern "C" void kernel_launch(void* const* d_in, const int* in_sizes, int n_in,
                              void* d_out, int out_size, void* d_ws, size_t ws_size,
                              hipStream_t stream) {
  (void)in_sizes; (void)n_in; (void)out_size; (void)ws_size;
  const float* hidden  = (const float*)d_in[0];
  const int*   key_seq = (const int*)d_in[1];
  const int*   vmat    = (const int*)d_in[2];
  const int*   mask    = (const int*)d_in[3];
  const float* key_emb = (const float*)d_in[4];
  const float* val_emb = (const float*)d_in[5];
  float* out = (float*)d_out;

  // ws layout (16B-aligned):
  //   VT8 : VAL_SIZE*H bytes   = 7,680,000 B
  //   ET2 : B*H2*K uint        = 1,572,864 B
  //   P   : B*L*K float        = 1,048,576 B
  unsigned char* VT8 = (unsigned char*)d_ws;
  unsigned*      ET2 = (unsigned*)(VT8 + (size_t)VAL_SIZE_ * H_);
  float*         P   = (float*)(ET2 + (size_t)B_ * H2_ * K_);

  k_gather_keys_T<<<TBLK, 256, 0, stream>>>(key_seq, key_emb, ET2);
  k_scores_convert<<<SBLK + CBLK, 256, 0, stream>>>(hidden, ET2, mask,
                                                    val_emb, P, VT8);
  k_pv_add<<<dim3(L_, B_), 384, 0, stream>>>(hidden, vmat, P, VT8, out);
}